// Round 1
// baseline (210.558 us; speedup 1.0000x reference)
//
#include <hip/hip_runtime.h>
#include <cstdint>
#include <cstddef>

#define T_SEQ 2048
#define D_EMB 1024
#define H_HEADS 16
#define HDIM 64
#define MROWS 4096   // M*T
#define SCALE_QK 0.03125f

typedef __attribute__((ext_vector_type(8))) short bf16x8;
typedef __attribute__((ext_vector_type(4))) float f32x4;
typedef __attribute__((ext_vector_type(4))) unsigned short us4;

__device__ __forceinline__ unsigned short f2bf(float f) {
  union { float f; uint32_t u; } v; v.f = f;
  uint32_t u = v.u;
  return (unsigned short)((u + 0x7FFFu + ((u >> 16) & 1u)) >> 16);
}

// ---------------- fp32 -> bf16 converter (weights) ----------------
__global__ __launch_bounds__(256) void cvt_f32_bf16(const float* __restrict__ in,
                                                    unsigned short* __restrict__ out,
                                                    int n4) {
  int i = blockIdx.x * 256 + threadIdx.x;
  if (i < n4) {
    float4 f = ((const float4*)in)[i];
    us4 o;
    o[0] = f2bf(f.x); o[1] = f2bf(f.y); o[2] = f2bf(f.z); o[3] = f2bf(f.w);
    ((us4*)out)[i] = o;
  }
}

// ---------------- GEMM: C = A @ W^T + bias ----------------
// A: [4096][1024] (fp32 if AMODE==0, bf16 if AMODE==1), W: [1024][1024] bf16 row-major (N x K)
// OMODE 0: bf16 out, row-major [4096][1024]
// OMODE 1: bf16 out, transposed per-head: vt[m][h][d][t]
// OMODE 2: fp32 out, row-major [4096][1024]
// Tile: BM=128, BN=64, BK=32. 4 waves, each computes 32x64.
template<int AMODE, int OMODE>
__global__ __launch_bounds__(256) void gemm_bt(const void* __restrict__ Aptr,
                                               const unsigned short* __restrict__ Bw,
                                               const float* __restrict__ bias,
                                               void* __restrict__ Outp) {
  __shared__ __align__(16) unsigned short Asm[128 * 40];
  __shared__ __align__(16) unsigned short Bsm[64 * 40];
  const int tid = threadIdx.x;
  const int lane = tid & 63, w = tid >> 6;
  const int fq = lane >> 4, fr = lane & 15;
  const int brow = blockIdx.y * 128, bcol = blockIdx.x * 64;

  f32x4 acc[2][4] = {};

  for (int k0 = 0; k0 < D_EMB; k0 += 32) {
    // stage A tile 128x32 (2 passes of 256 threads x 8 elems)
#pragma unroll
    for (int p = 0; p < 2; ++p) {
      int t = p * 256 + tid;
      int row = t >> 2, c = (t & 3) * 8;
      bf16x8 av;
      if (AMODE == 0) {
        const float* A = (const float*)Aptr;
        const float* g = &A[(size_t)(brow + row) * D_EMB + k0 + c];
        float4 f0 = *(const float4*)g;
        float4 f1 = *(const float4*)(g + 4);
        av[0] = (short)f2bf(f0.x); av[1] = (short)f2bf(f0.y);
        av[2] = (short)f2bf(f0.z); av[3] = (short)f2bf(f0.w);
        av[4] = (short)f2bf(f1.x); av[5] = (short)f2bf(f1.y);
        av[6] = (short)f2bf(f1.z); av[7] = (short)f2bf(f1.w);
      } else {
        const unsigned short* A = (const unsigned short*)Aptr;
        av = *(const bf16x8*)&A[(size_t)(brow + row) * D_EMB + k0 + c];
      }
      *(bf16x8*)&Asm[row * 40 + c] = av;
    }
    // stage B tile 64x32 (1 pass)
    {
      int row = tid >> 2, c = (tid & 3) * 8;
      bf16x8 bv = *(const bf16x8*)&Bw[(size_t)(bcol + row) * D_EMB + k0 + c];
      *(bf16x8*)&Bsm[row * 40 + c] = bv;
    }
    __syncthreads();

    bf16x8 af[2], bfr[4];
#pragma unroll
    for (int i = 0; i < 2; ++i)
      af[i] = *(const bf16x8*)&Asm[(w * 32 + i * 16 + fr) * 40 + fq * 8];
#pragma unroll
    for (int j = 0; j < 4; ++j)
      bfr[j] = *(const bf16x8*)&Bsm[(j * 16 + fr) * 40 + fq * 8];
#pragma unroll
    for (int i = 0; i < 2; ++i)
#pragma unroll
      for (int j = 0; j < 4; ++j)
        acc[i][j] = __builtin_amdgcn_mfma_f32_16x16x32_bf16(af[i], bfr[j], acc[i][j], 0, 0, 0);
    __syncthreads();
  }

  // epilogue
#pragma unroll
  for (int i = 0; i < 2; ++i) {
#pragma unroll
    for (int j = 0; j < 4; ++j) {
      int r0 = brow + w * 32 + i * 16 + fq * 4;
      int cc = bcol + j * 16 + fr;
      float bb = bias[cc];
      if (OMODE == 0) {
        unsigned short* O = (unsigned short*)Outp;
#pragma unroll
        for (int q = 0; q < 4; ++q)
          O[(size_t)(r0 + q) * D_EMB + cc] = f2bf(acc[i][j][q] + bb);
      } else if (OMODE == 1) {
        unsigned short* O = (unsigned short*)Outp;
        int hh = cc >> 6, dd = cc & 63;
        int mm = r0 >> 11, tt = r0 & 2047;
        us4 pk;
#pragma unroll
        for (int q = 0; q < 4; ++q) pk[q] = f2bf(acc[i][j][q] + bb);
        *(us4*)&O[((size_t)((mm * H_HEADS + hh) * HDIM + dd)) * T_SEQ + tt] = pk;
      } else {
        float* O = (float*)Outp;
#pragma unroll
        for (int q = 0; q < 4; ++q)
          O[(size_t)(r0 + q) * D_EMB + cc] = acc[i][j][q] + bb;
      }
    }
  }
}

// ---------------- Flash attention ----------------
// grid: (T/64, H, M). block: 256 (4 waves, each 16 q-rows).
// q,k: bf16 [m*T + t][1024] row-major (head h at cols h*64..h*64+63)
// vt : bf16 [((m*16+h)*64 + d)][2048]
// out: bf16 [m*T + t][1024] (concat layout)
__global__ __launch_bounds__(256) void attn_fwd(const unsigned short* __restrict__ qb,
                                                const unsigned short* __restrict__ kb,
                                                const unsigned short* __restrict__ vtb,
                                                const int* __restrict__ mask,
                                                unsigned short* __restrict__ outb) {
  const int qt = blockIdx.x, h = blockIdx.y, mI = blockIdx.z;
  const int tid = threadIdx.x;
  const int lane = tid & 63, w = tid >> 6;
  const int fq = lane >> 4, fr = lane & 15;

  __shared__ __align__(16) unsigned short Ksm[64 * 72];
  __shared__ __align__(16) unsigned short Vsm[64 * 72];
  __shared__ __align__(16) float Msm[64];
  __shared__ __align__(16) unsigned short Psm[4][16 * 88];

  const int qrow = qt * 64 + w * 16 + fr;
  bf16x8 qf[2];
#pragma unroll
  for (int kk = 0; kk < 2; ++kk)
    qf[kk] = *(const bf16x8*)&qb[((size_t)(mI * T_SEQ) + qrow) * D_EMB + h * HDIM + kk * 32 + fq * 8];

  f32x4 o[4] = {};
  float mi = -1e30f, li = 0.f;

  for (int k0 = 0; k0 < T_SEQ; k0 += 64) {
    // stage K tile [64 keys][64 d] and Vt tile [64 d][64 keys]
#pragma unroll
    for (int p = 0; p < 2; ++p) {
      int t = p * 256 + tid;
      int row = t >> 3, c = (t & 7) * 8;
      *(bf16x8*)&Ksm[row * 72 + c] =
          *(const bf16x8*)&kb[((size_t)(mI * T_SEQ) + k0 + row) * D_EMB + h * HDIM + c];
      *(bf16x8*)&Vsm[row * 72 + c] =
          *(const bf16x8*)&vtb[((size_t)((mI * H_HEADS + h) * HDIM) + row) * T_SEQ + k0 + c];
    }
    if (tid < 64) Msm[tid] = (mask[mI * T_SEQ + k0 + tid] == 0) ? -1e20f : 0.f;
    __syncthreads();

    // S^T[key][q] = K · Q^T  (swapped so each lane holds one q-column)
    f32x4 s[4] = {};
#pragma unroll
    for (int mt = 0; mt < 4; ++mt) {
#pragma unroll
      for (int kk = 0; kk < 2; ++kk) {
        bf16x8 ak = *(const bf16x8*)&Ksm[(mt * 16 + fr) * 72 + kk * 32 + fq * 8];
        s[mt] = __builtin_amdgcn_mfma_f32_16x16x32_bf16(ak, qf[kk], s[mt], 0, 0, 0);
      }
    }

    // scale + mask + tile max
    float tmax = -1e30f;
#pragma unroll
    for (int mt = 0; mt < 4; ++mt) {
      f32x4 mk = *(const f32x4*)&Msm[mt * 16 + fq * 4];
#pragma unroll
      for (int j = 0; j < 4; ++j) {
        float sv = s[mt][j] * SCALE_QK + mk[j];
        s[mt][j] = sv;
        tmax = fmaxf(tmax, sv);
      }
    }
    tmax = fmaxf(tmax, __shfl_xor(tmax, 16));
    tmax = fmaxf(tmax, __shfl_xor(tmax, 32));

    float mnew = fmaxf(mi, tmax);
    float corr = __expf(mi - mnew);
    float ts = 0.f;
#pragma unroll
    for (int mt = 0; mt < 4; ++mt)
#pragma unroll
      for (int j = 0; j < 4; ++j) {
        float p_ = __expf(s[mt][j] - mnew);
        s[mt][j] = p_;
        ts += p_;
      }
    ts += __shfl_xor(ts, 16);
    ts += __shfl_xor(ts, 32);
    li = li * corr + ts;
    mi = mnew;

    // write P (bf16) into per-wave LDS in A-fragment ([q][key]) layout
#pragma unroll
    for (int mt = 0; mt < 4; ++mt) {
      us4 pk;
#pragma unroll
      for (int j = 0; j < 4; ++j) pk[j] = f2bf(s[mt][j]);
      *(us4*)&Psm[w][fr * 88 + mt * 16 + fq * 4] = pk;
    }

    // rescale accumulator (acc rows are q = fq*4+j, stats live at lane q)
    float c0 = __shfl(corr, fq * 4 + 0);
    float c1 = __shfl(corr, fq * 4 + 1);
    float c2 = __shfl(corr, fq * 4 + 2);
    float c3 = __shfl(corr, fq * 4 + 3);
#pragma unroll
    for (int nt = 0; nt < 4; ++nt) {
      o[nt][0] *= c0; o[nt][1] *= c1; o[nt][2] *= c2; o[nt][3] *= c3;
    }

    // PV: out[q][d] += P · Vt^T
    bf16x8 ap[2];
#pragma unroll
    for (int kk = 0; kk < 2; ++kk)
      ap[kk] = *(const bf16x8*)&Psm[w][fr * 88 + kk * 32 + fq * 8];
#pragma unroll
    for (int nt = 0; nt < 4; ++nt)
#pragma unroll
      for (int kk = 0; kk < 2; ++kk) {
        bf16x8 bv = *(const bf16x8*)&Vsm[(nt * 16 + fr) * 72 + kk * 32 + fq * 8];
        o[nt] = __builtin_amdgcn_mfma_f32_16x16x32_bf16(ap[kk], bv, o[nt], 0, 0, 0);
      }
    __syncthreads();
  }

  // epilogue: divide by li (per output row q' = fq*4+j) and store bf16
  float l0 = __shfl(li, fq * 4 + 0), l1 = __shfl(li, fq * 4 + 1);
  float l2 = __shfl(li, fq * 4 + 2), l3 = __shfl(li, fq * 4 + 3);
  float i0 = 1.f / l0, i1 = 1.f / l1, i2 = 1.f / l2, i3 = 1.f / l3;
  int rbase = mI * T_SEQ + qt * 64 + w * 16 + fq * 4;
#pragma unroll
  for (int nt = 0; nt < 4; ++nt) {
    int col = h * HDIM + nt * 16 + fr;
    outb[(size_t)(rbase + 0) * D_EMB + col] = f2bf(o[nt][0] * i0);
    outb[(size_t)(rbase + 1) * D_EMB + col] = f2bf(o[nt][1] * i1);
    outb[(size_t)(rbase + 2) * D_EMB + col] = f2bf(o[nt][2] * i2);
    outb[(size_t)(rbase + 3) * D_EMB + col] = f2bf(o[nt][3] * i3);
  }
}

extern "C" void kernel_launch(void* const* d_in, const int* in_sizes, int n_in,
                              void* d_out, int out_size, void* d_ws, size_t ws_size,
                              hipStream_t stream) {
  const float* Q  = (const float*)d_in[0];
  const float* K  = (const float*)d_in[1];
  const float* V  = (const float*)d_in[2];
  const int* mask = (const int*)d_in[3];
  const float* Wq = (const float*)d_in[4];
  const float* bq = (const float*)d_in[5];
  const float* Wk = (const float*)d_in[6];
  const float* bk = (const float*)d_in[7];
  const float* Wv = (const float*)d_in[8];
  const float* bv = (const float*)d_in[9];
  const float* Wo = (const float*)d_in[10];
  const float* bo = (const float*)d_in[11];

  uint8_t* ws = (uint8_t*)d_ws;
  const size_t MB = 1u << 20;
  unsigned short* Wq_b = (unsigned short*)(ws + 0 * MB);
  unsigned short* Wk_b = (unsigned short*)(ws + 2 * MB);
  unsigned short* Wv_b = (unsigned short*)(ws + 4 * MB);
  unsigned short* Wo_b = (unsigned short*)(ws + 6 * MB);
  unsigned short* q_b  = (unsigned short*)(ws + 8 * MB);
  unsigned short* k_b  = (unsigned short*)(ws + 16 * MB);
  unsigned short* vt_b = (unsigned short*)(ws + 24 * MB);
  unsigned short* cc_b = (unsigned short*)(ws + 32 * MB);

  const int n4 = (D_EMB * D_EMB) / 4;
  cvt_f32_bf16<<<dim3(n4 / 256), dim3(256), 0, stream>>>(Wq, Wq_b, n4);
  cvt_f32_bf16<<<dim3(n4 / 256), dim3(256), 0, stream>>>(Wk, Wk_b, n4);
  cvt_f32_bf16<<<dim3(n4 / 256), dim3(256), 0, stream>>>(Wv, Wv_b, n4);
  cvt_f32_bf16<<<dim3(n4 / 256), dim3(256), 0, stream>>>(Wo, Wo_b, n4);

  dim3 gg(D_EMB / 64, MROWS / 128), gb(256);
  gemm_bt<0, 0><<<gg, gb, 0, stream>>>(Q, Wq_b, bq, q_b);
  gemm_bt<0, 0><<<gg, gb, 0, stream>>>(K, Wk_b, bk, k_b);
  gemm_bt<0, 1><<<gg, gb, 0, stream>>>(V, Wv_b, bv, vt_b);

  attn_fwd<<<dim3(T_SEQ / 64, H_HEADS, 2), dim3(256), 0, stream>>>(q_b, k_b, vt_b, mask, cc_b);

  gemm_bt<1, 2><<<gg, gb, 0, stream>>>(cc_b, Wo_b, bo, d_out);
}

// Round 3
// 182.570 us; speedup vs baseline: 1.1533x; 1.1533x over previous
//
#include <hip/hip_runtime.h>
#include <cstdint>
#include <cstddef>

#define T_SEQ 2048
#define D_EMB 1024
#define H_HEADS 16
#define MROWS 4096
// scale * log2(e): softmax computed in exp2 domain
#define SC2 (0.03125f * 1.44269504f)
#define MASKNEG (-1e30f)

typedef __attribute__((ext_vector_type(8))) short bf16x8;
typedef __attribute__((ext_vector_type(4))) float f32x4;
typedef __attribute__((ext_vector_type(4))) unsigned short us4;

__device__ __forceinline__ unsigned short f2bf(float f) {
  union { float f; uint32_t u; } v; v.f = f;
  uint32_t u = v.u;
  return (unsigned short)((u + 0x7FFFu + ((u >> 16) & 1u)) >> 16);
}

__device__ __forceinline__ uint32_t cvtpk(float lo, float hi) {
  uint32_t r;
  asm("v_cvt_pk_bf16_f32 %0, %1, %2" : "=v"(r) : "v"(lo), "v"(hi));
  return r;
}

__device__ __forceinline__ float fexp2(float x) {
  float r;
  asm("v_exp_f32 %0, %1" : "=v"(r) : "v"(x));
  return r;
}

__device__ __forceinline__ void gl16(const void* g, void* l) {
  __builtin_amdgcn_global_load_lds(
      (const __attribute__((address_space(1))) unsigned int*)g,
      (__attribute__((address_space(3))) unsigned int*)l, 16, 0, 0);
}

// ---------------- fp32 -> bf16 (weights) ----------------
__global__ __launch_bounds__(256) void cvt_f32_bf16(const float* __restrict__ in,
                                                    unsigned short* __restrict__ out,
                                                    int n4) {
  int i = blockIdx.x * 256 + threadIdx.x;
  if (i < n4) {
    float4 f = ((const float4*)in)[i];
    us4 o;
    o[0] = f2bf(f.x); o[1] = f2bf(f.y); o[2] = f2bf(f.z); o[3] = f2bf(f.w);
    ((us4*)out)[i] = o;
  }
}

// ---------------- fused QKV projection GEMM ----------------
// grid (8, 32, 3): z selects (Q,Wq)->q_b row-major, (K,Wk)->k_b row-major,
// (V,Wv)->vt transposed per head. BM=128 BN=128 BK=32, 4 waves, acc 4x4.
// A fp32 staged via global_load_lds into XOR-swizzled LDS, cvt_pk at frag read.
__global__ __launch_bounds__(256) void qkv_gemm(
    const float* __restrict__ Qf, const float* __restrict__ Kf, const float* __restrict__ Vf,
    const unsigned short* __restrict__ Wqb, const unsigned short* __restrict__ Wkb,
    const unsigned short* __restrict__ Wvb,
    const float* __restrict__ bq, const float* __restrict__ bk, const float* __restrict__ bv,
    unsigned short* __restrict__ qo, unsigned short* __restrict__ ko,
    unsigned short* __restrict__ vto) {
  const int z = blockIdx.z;
  const float* A = (z == 0) ? Qf : (z == 1) ? Kf : Vf;
  const unsigned short* W = (z == 0) ? Wqb : (z == 1) ? Wkb : Wvb;
  const float* bias = (z == 0) ? bq : (z == 1) ? bk : bv;

  __shared__ __align__(16) float Asm[128 * 32];          // fp32, swizzled
  __shared__ __align__(16) unsigned short Bsm[128 * 32]; // bf16, linear

  const int tid = threadIdx.x;
  const int lane = tid & 63, w = tid >> 6;
  const int fq = lane >> 4, fr = lane & 15;
  const int brow = blockIdx.y * 128, bcol = blockIdx.x * 128;
  const int wr = (w >> 1) * 64, wc = (w & 1) * 64;

  f32x4 acc[4][4] = {};

  for (int k0 = 0; k0 < D_EMB; k0 += 32) {
    // stage A: 128 rows x 128B, pre-swizzled source
#pragma unroll
    for (int it = 0; it < 4; ++it) {
      int idx = it * 256 + tid;
      int row = idx >> 3;
      int sb = ((idx & 7) * 16) ^ ((row & 7) << 4);
      gl16(&A[(size_t)(brow + row) * D_EMB + k0 + (sb >> 2)], (char*)Asm + idx * 16);
    }
    // stage B: 128 rows x 64B, linear
#pragma unroll
    for (int it = 0; it < 2; ++it) {
      int idx = it * 256 + tid;
      int row = idx >> 2;
      int cb = (idx & 3) * 16;
      gl16(&W[(size_t)(bcol + row) * D_EMB + k0 + (cb >> 1)], (char*)Bsm + idx * 16);
    }
    __syncthreads();

    bf16x8 af[4], bfr[4];
#pragma unroll
    for (int i = 0; i < 4; ++i) {
      int row = wr + i * 16 + fr;
      int x = (row & 7) << 4;
      const char* base = (const char*)Asm + row * 128;
      f32x4 lo = *(const f32x4*)(base + ((fq * 32) ^ x));
      f32x4 hi = *(const f32x4*)(base + ((fq * 32 + 16) ^ x));
      union { bf16x8 v; uint32_t u[4]; } a_;
      a_.u[0] = cvtpk(lo[0], lo[1]); a_.u[1] = cvtpk(lo[2], lo[3]);
      a_.u[2] = cvtpk(hi[0], hi[1]); a_.u[3] = cvtpk(hi[2], hi[3]);
      af[i] = a_.v;
    }
#pragma unroll
    for (int j = 0; j < 4; ++j)
      bfr[j] = *(const bf16x8*)((const char*)Bsm + (wc + j * 16 + fr) * 64 + fq * 16);
#pragma unroll
    for (int i = 0; i < 4; ++i)
#pragma unroll
      for (int j = 0; j < 4; ++j)
        acc[i][j] = __builtin_amdgcn_mfma_f32_16x16x32_bf16(af[i], bfr[j], acc[i][j], 0, 0, 0);
    __syncthreads();
  }

  // epilogue
#pragma unroll
  for (int i = 0; i < 4; ++i) {
#pragma unroll
    for (int j = 0; j < 4; ++j) {
      int r0 = brow + wr + i * 16 + fq * 4;
      int cc = bcol + wc + j * 16 + fr;
      float bb = bias[cc];
      if (z < 2) {
        unsigned short* O = (z == 0) ? qo : ko;
#pragma unroll
        for (int q = 0; q < 4; ++q)
          O[(size_t)(r0 + q) * D_EMB + cc] = f2bf(acc[i][j][q] + bb);
      } else {
        int hh = cc >> 6, dd = cc & 63;
        int mm = r0 >> 11, tt = r0 & 2047;
        us4 pk;
#pragma unroll
        for (int q = 0; q < 4; ++q) pk[q] = f2bf(acc[i][j][q] + bb);
        *(us4*)&vto[((size_t)((mm * H_HEADS + hh) * 64 + dd)) * T_SEQ + tt] = pk;
      }
    }
  }
}

// ---------------- output projection GEMM ----------------
// BM=128 BN=64 BK=32, bf16 A, fp32 out. grid (16, 32).
__global__ __launch_bounds__(256) void out_gemm(const unsigned short* __restrict__ Ab,
                                                const unsigned short* __restrict__ Wb,
                                                const float* __restrict__ bias,
                                                float* __restrict__ Out) {
  __shared__ __align__(16) unsigned short Asm[128 * 32];
  __shared__ __align__(16) unsigned short Bsm[64 * 32];
  const int tid = threadIdx.x;
  const int lane = tid & 63, w = tid >> 6;
  const int fq = lane >> 4, fr = lane & 15;
  const int brow = blockIdx.y * 128, bcol = blockIdx.x * 64;
  const int wr = w * 32;

  f32x4 acc[2][4] = {};

  for (int k0 = 0; k0 < D_EMB; k0 += 32) {
#pragma unroll
    for (int it = 0; it < 2; ++it) {
      int idx = it * 256 + tid;
      int row = idx >> 2, cb = (idx & 3) * 16;
      gl16(&Ab[(size_t)(brow + row) * D_EMB + k0 + (cb >> 1)], (char*)Asm + idx * 16);
    }
    {
      int row = tid >> 2, cb = (tid & 3) * 16;
      gl16(&Wb[(size_t)(bcol + row) * D_EMB + k0 + (cb >> 1)], (char*)Bsm + tid * 16);
    }
    __syncthreads();

    bf16x8 af[2], bfr[4];
#pragma unroll
    for (int i = 0; i < 2; ++i)
      af[i] = *(const bf16x8*)((const char*)Asm + (wr + i * 16 + fr) * 64 + fq * 16);
#pragma unroll
    for (int j = 0; j < 4; ++j)
      bfr[j] = *(const bf16x8*)((const char*)Bsm + (j * 16 + fr) * 64 + fq * 16);
#pragma unroll
    for (int i = 0; i < 2; ++i)
#pragma unroll
      for (int j = 0; j < 4; ++j)
        acc[i][j] = __builtin_amdgcn_mfma_f32_16x16x32_bf16(af[i], bfr[j], acc[i][j], 0, 0, 0);
    __syncthreads();
  }

#pragma unroll
  for (int i = 0; i < 2; ++i)
#pragma unroll
    for (int j = 0; j < 4; ++j) {
      int r0 = brow + wr + i * 16 + fq * 4;
      int cc = bcol + j * 16 + fr;
      float bb = bias[cc];
#pragma unroll
      for (int q = 0; q < 4; ++q)
        Out[(size_t)(r0 + q) * D_EMB + cc] = acc[i][j][q] + bb;
    }
}

// ---------------- Flash attention ----------------
// grid (32, 16, 2), block 256 (4 waves x 16 q-rows = 64 q-rows/block). KVBLK=128.
// K,V staged via global_load_lds with pre-swizzled source; swapped QK^T and
// swapped PV so per-q stats (m,l) live in the owning lane (no broadcasts).
__global__ __launch_bounds__(256) void attn_fwd(const unsigned short* __restrict__ qb,
                                                const unsigned short* __restrict__ kb,
                                                const unsigned short* __restrict__ vtb,
                                                const int* __restrict__ maskg,
                                                unsigned short* __restrict__ outb) {
  const int qt = blockIdx.x, h = blockIdx.y, mI = blockIdx.z;
  const int tid = threadIdx.x;
  const int lane = tid & 63, w = tid >> 6;
  const int fq = lane >> 4, fr = lane & 15;
  const int x_fr = (fr & 7) << 4;

  __shared__ __align__(16) unsigned short Ksm[128 * 64];  // [t][d], swizzled
  __shared__ __align__(16) unsigned short Vsm[64 * 128];  // [d][t], swizzled
  __shared__ __align__(16) unsigned short Psm[4][16 * 128]; // per-wave [q][t], swizzled
  __shared__ __align__(16) float Msm[128];

  char* KsmB = (char*)Ksm;
  char* VsmB = (char*)Vsm;
  char* PsmB = (char*)Psm + w * 4096;

  const int qrow = qt * 64 + w * 16 + fr;
  bf16x8 qf[2];
#pragma unroll
  for (int kk = 0; kk < 2; ++kk)
    qf[kk] = *(const bf16x8*)&qb[((size_t)(mI * T_SEQ) + qrow) * D_EMB + h * 64 + kk * 32 + fq * 8];

  f32x4 o[4] = {};
  float mi = -1e30f, li = 0.f;

  const unsigned short* kpan = kb + (size_t)(mI * T_SEQ) * D_EMB + h * 64;
  const unsigned short* vpan = vtb + (size_t)(mI * H_HEADS + h) * 64 * T_SEQ;

  for (int k0 = 0; k0 < T_SEQ; k0 += 128) {
    // ---- stage K [128][64] ----
#pragma unroll
    for (int it = 0; it < 4; ++it) {
      int idx = it * 256 + tid;
      int row = idx >> 3;
      int sb = ((idx & 7) * 16) ^ ((row & 7) << 4);
      gl16(kpan + (size_t)(k0 + row) * D_EMB + (sb >> 1), KsmB + idx * 16);
    }
    // ---- stage Vt [64][128] ----
#pragma unroll
    for (int it = 0; it < 4; ++it) {
      int idx = it * 256 + tid;
      int row = idx >> 4;
      int sb = ((idx & 15) * 16) ^ ((row & 7) << 4);
      gl16(vpan + (size_t)row * T_SEQ + k0 + (sb >> 1), VsmB + idx * 16);
    }
    if (tid < 128) Msm[tid] = (maskg[mI * T_SEQ + k0 + tid] == 0) ? MASKNEG : 0.f;
    __syncthreads();

    // ---- S^T[key][q] = K · Q^T ----
    f32x4 s[8];
#pragma unroll
    for (int mt = 0; mt < 8; ++mt) {
      const char* kr = KsmB + (mt * 16 + fr) * 128;
      bf16x8 a0 = *(const bf16x8*)(kr + ((fq * 16) ^ x_fr));
      bf16x8 a1 = *(const bf16x8*)(kr + ((64 + fq * 16) ^ x_fr));
      f32x4 t = {};
      t = __builtin_amdgcn_mfma_f32_16x16x32_bf16(a0, qf[0], t, 0, 0, 0);
      t = __builtin_amdgcn_mfma_f32_16x16x32_bf16(a1, qf[1], t, 0, 0, 0);
      s[mt] = t;
    }

    // ---- scaled+masked logits (exp2 domain), tile max ----
    float tmax = -3e38f;
#pragma unroll
    for (int mt = 0; mt < 8; ++mt) {
      f32x4 mk = *(const f32x4*)&Msm[mt * 16 + fq * 4];
#pragma unroll
      for (int j = 0; j < 4; ++j) {
        float sv = fmaf(s[mt][j], SC2, mk[j]);
        s[mt][j] = sv;
        tmax = fmaxf(tmax, sv);
      }
    }
    tmax = fmaxf(tmax, __shfl_xor(tmax, 16));
    tmax = fmaxf(tmax, __shfl_xor(tmax, 32));

    // ---- defer-max rescale (THR=8 in log2 domain) ----
    if (__any(tmax > mi + 8.f)) {
      float mnew = fmaxf(mi, tmax);
      float corr = fexp2(mi - mnew);
#pragma unroll
      for (int nt = 0; nt < 4; ++nt) {
        o[nt][0] *= corr; o[nt][1] *= corr; o[nt][2] *= corr; o[nt][3] *= corr;
      }
      li *= corr;
      mi = mnew;
    }

    // ---- P = exp2(s - mi), row sum ----
    float ts = 0.f;
#pragma unroll
    for (int mt = 0; mt < 8; ++mt)
#pragma unroll
      for (int j = 0; j < 4; ++j) {
        float p = fexp2(s[mt][j] - mi);
        s[mt][j] = p;
        ts += p;
      }
    ts += __shfl_xor(ts, 16);
    ts += __shfl_xor(ts, 32);
    li += ts;

    // ---- pack P to bf16, store per-wave swizzled LDS [q=fr][key] ----
#pragma unroll
    for (int mt = 0; mt < 8; ++mt) {
      uint2 pw;
      pw.x = cvtpk(s[mt][0], s[mt][1]);
      pw.y = cvtpk(s[mt][2], s[mt][3]);
      *(uint2*)(PsmB + fr * 256 + ((mt * 32 + fq * 8) ^ x_fr)) = pw;
    }

    // ---- PV: o^T[d][q] += Vt · P ----
    bf16x8 pb[4];
#pragma unroll
    for (int kk = 0; kk < 4; ++kk)
      pb[kk] = *(const bf16x8*)(PsmB + fr * 256 + ((kk * 64 + fq * 16) ^ x_fr));
#pragma unroll
    for (int nt = 0; nt < 4; ++nt) {
      const char* vr = VsmB + (nt * 16 + fr) * 256;
#pragma unroll
      for (int kk = 0; kk < 4; ++kk) {
        bf16x8 va = *(const bf16x8*)(vr + ((kk * 64 + fq * 16) ^ x_fr));
        o[nt] = __builtin_amdgcn_mfma_f32_16x16x32_bf16(va, pb[kk], o[nt], 0, 0, 0);
      }
    }
    __syncthreads();
  }

  // ---- epilogue: divide by own-lane li, coalesced uint2 stores ----
  float inv = 1.f / li;
  size_t orow = (size_t)(mI * T_SEQ + qt * 64 + w * 16 + fr) * D_EMB + h * 64;
#pragma unroll
  for (int nt = 0; nt < 4; ++nt) {
    uint2 ow;
    ow.x = cvtpk(o[nt][0] * inv, o[nt][1] * inv);
    ow.y = cvtpk(o[nt][2] * inv, o[nt][3] * inv);
    *(uint2*)&outb[orow + nt * 16 + fq * 4] = ow;
  }
}

extern "C" void kernel_launch(void* const* d_in, const int* in_sizes, int n_in,
                              void* d_out, int out_size, void* d_ws, size_t ws_size,
                              hipStream_t stream) {
  const float* Q  = (const float*)d_in[0];
  const float* K  = (const float*)d_in[1];
  const float* V  = (const float*)d_in[2];
  const int* mask = (const int*)d_in[3];
  const float* Wq = (const float*)d_in[4];
  const float* bq = (const float*)d_in[5];
  const float* Wk = (const float*)d_in[6];
  const float* bk = (const float*)d_in[7];
  const float* Wv = (const float*)d_in[8];
  const float* bv = (const float*)d_in[9];
  const float* Wo = (const float*)d_in[10];
  const float* bo = (const float*)d_in[11];

  uint8_t* ws = (uint8_t*)d_ws;
  const size_t MB = 1u << 20;
  unsigned short* Wq_b = (unsigned short*)(ws + 0 * MB);
  unsigned short* Wk_b = (unsigned short*)(ws + 2 * MB);
  unsigned short* Wv_b = (unsigned short*)(ws + 4 * MB);
  unsigned short* Wo_b = (unsigned short*)(ws + 6 * MB);
  unsigned short* q_b  = (unsigned short*)(ws + 8 * MB);
  unsigned short* k_b  = (unsigned short*)(ws + 16 * MB);
  unsigned short* vt_b = (unsigned short*)(ws + 24 * MB);
  unsigned short* cc_b = (unsigned short*)(ws + 32 * MB);

  const int n4 = (D_EMB * D_EMB) / 4;
  cvt_f32_bf16<<<dim3(n4 / 256), dim3(256), 0, stream>>>(Wq, Wq_b, n4);
  cvt_f32_bf16<<<dim3(n4 / 256), dim3(256), 0, stream>>>(Wk, Wk_b, n4);
  cvt_f32_bf16<<<dim3(n4 / 256), dim3(256), 0, stream>>>(Wv, Wv_b, n4);
  cvt_f32_bf16<<<dim3(n4 / 256), dim3(256), 0, stream>>>(Wo, Wo_b, n4);

  qkv_gemm<<<dim3(D_EMB / 128, MROWS / 128, 3), dim3(256), 0, stream>>>(
      Q, K, V, Wq_b, Wk_b, Wv_b, bq, bk, bv, q_b, k_b, vt_b);

  attn_fwd<<<dim3(T_SEQ / 64, H_HEADS, 2), dim3(256), 0, stream>>>(
      q_b, k_b, vt_b, mask, cc_b);

  out_gemm<<<dim3(D_EMB / 64, MROWS / 128), dim3(256), 0, stream>>>(
      cc_b, Wo_b, bo, (float*)d_out);
}

// Round 4
// 149.350 us; speedup vs baseline: 1.4098x; 1.2224x over previous
//
#include <hip/hip_runtime.h>
#include <cstdint>
#include <cstddef>

#define T_SEQ 2048
#define D_EMB 1024
#define H_HEADS 16
#define MROWS 4096
// scale * log2(e): softmax computed in exp2 domain
#define SC2 (0.03125f * 1.44269504f)
#define MASKNEG (-1e30f)

typedef __attribute__((ext_vector_type(8))) short bf16x8;
typedef __attribute__((ext_vector_type(4))) float f32x4;
typedef __attribute__((ext_vector_type(4))) unsigned short us4;

__device__ __forceinline__ unsigned short f2bf(float f) {
  union { float f; uint32_t u; } v; v.f = f;
  uint32_t u = v.u;
  return (unsigned short)((u + 0x7FFFu + ((u >> 16) & 1u)) >> 16);
}

__device__ __forceinline__ uint32_t cvtpk(float lo, float hi) {
  uint32_t r;
  asm("v_cvt_pk_bf16_f32 %0, %1, %2" : "=v"(r) : "v"(lo), "v"(hi));
  return r;
}

__device__ __forceinline__ float fexp2(float x) {
  float r;
  asm("v_exp_f32 %0, %1" : "=v"(r) : "v"(x));
  return r;
}

__device__ __forceinline__ void gl16(const void* g, void* l) {
  __builtin_amdgcn_global_load_lds(
      (const __attribute__((address_space(1))) unsigned int*)g,
      (__attribute__((address_space(3))) unsigned int*)l, 16, 0, 0);
}

// ---------------- fused fp32 -> bf16 (3 inputs + 4 weights, one dispatch) ----------------
// quads: Q/K/V 1048576 each, weights 262144 each. total 4194304 quads.
__global__ __launch_bounds__(256) void cvt_all(
    const float* __restrict__ Q, const float* __restrict__ K, const float* __restrict__ V,
    const float* __restrict__ Wq, const float* __restrict__ Wk,
    const float* __restrict__ Wv, const float* __restrict__ Wo,
    unsigned short* __restrict__ Qb, unsigned short* __restrict__ Kb,
    unsigned short* __restrict__ Vb,
    unsigned short* __restrict__ Wqb, unsigned short* __restrict__ Wkb,
    unsigned short* __restrict__ Wvb, unsigned short* __restrict__ Wob) {
  int i = blockIdx.x * 256 + threadIdx.x;
  const float* src;
  unsigned short* dst;
  int j;
  if (i < 3145728) {
    int s = i >> 20;
    j = i & 1048575;
    src = (s == 0) ? Q : (s == 1) ? K : V;
    dst = (s == 0) ? Qb : (s == 1) ? Kb : Vb;
  } else {
    int k = i - 3145728;
    int s = k >> 18;
    j = k & 262143;
    src = (s == 0) ? Wq : (s == 1) ? Wk : (s == 2) ? Wv : Wo;
    dst = (s == 0) ? Wqb : (s == 1) ? Wkb : (s == 2) ? Wvb : Wob;
  }
  float4 f = ((const float4*)src)[j];
  us4 o;
  o[0] = f2bf(f.x); o[1] = f2bf(f.y); o[2] = f2bf(f.z); o[3] = f2bf(f.w);
  ((us4*)dst)[j] = o;
}

// ---------------- fused QKV projection GEMM ----------------
// 1D grid 768 blocks, XCD-swizzled: all 8 bcol-blocks of an A panel -> same XCD.
// BM=128 BN=128 BK=32, bf16 A, 4 waves, acc 4x4, double-buffered 2-phase K-loop.
__global__ __launch_bounds__(256) void qkv_gemm(
    const unsigned short* __restrict__ Qb, const unsigned short* __restrict__ Kb,
    const unsigned short* __restrict__ Vb,
    const unsigned short* __restrict__ Wqb, const unsigned short* __restrict__ Wkb,
    const unsigned short* __restrict__ Wvb,
    const float* __restrict__ bq, const float* __restrict__ bk, const float* __restrict__ bv,
    unsigned short* __restrict__ qo, unsigned short* __restrict__ ko,
    unsigned short* __restrict__ vto) {
  const int swz = (blockIdx.x & 7) * 96 + (blockIdx.x >> 3);
  const int bx = swz & 7, by = (swz >> 3) & 31, z = swz >> 8;
  const unsigned short* A = (z == 0) ? Qb : (z == 1) ? Kb : Vb;
  const unsigned short* W = (z == 0) ? Wqb : (z == 1) ? Wkb : Wvb;
  const float* bias = (z == 0) ? bq : (z == 1) ? bk : bv;

  __shared__ __align__(16) unsigned short Asm[2][128 * 32];
  __shared__ __align__(16) unsigned short Bsm[2][128 * 32];

  const int tid = threadIdx.x;
  const int lane = tid & 63, w = tid >> 6;
  const int fq = lane >> 4, fr = lane & 15;
  const int brow = by * 128, bcol = bx * 128;
  const int wr = (w >> 1) * 64, wc = (w & 1) * 64;

  f32x4 acc[4][4] = {};

#define QKV_STAGE(buf, k0)                                                     \
  {                                                                            \
    _Pragma("unroll") for (int it = 0; it < 2; ++it) {                         \
      int idx = it * 256 + tid;                                                \
      int row = idx >> 2, ce = (idx & 3) * 8;                                  \
      gl16(&A[(size_t)(brow + row) * D_EMB + (k0) + ce],                       \
           (char*)Asm[buf] + idx * 16);                                        \
      gl16(&W[(size_t)(bcol + row) * D_EMB + (k0) + ce],                       \
           (char*)Bsm[buf] + idx * 16);                                        \
    }                                                                          \
  }

#define QKV_COMPUTE(buf)                                                       \
  {                                                                            \
    bf16x8 af[4], bfr[4];                                                      \
    _Pragma("unroll") for (int i = 0; i < 4; ++i)                              \
        af[i] = *(const bf16x8*)((const char*)Asm[buf] +                       \
                                 (wr + i * 16 + fr) * 64 + fq * 16);           \
    _Pragma("unroll") for (int j = 0; j < 4; ++j)                              \
        bfr[j] = *(const bf16x8*)((const char*)Bsm[buf] +                      \
                                  (wc + j * 16 + fr) * 64 + fq * 16);          \
    _Pragma("unroll") for (int i = 0; i < 4; ++i)                              \
        _Pragma("unroll") for (int j = 0; j < 4; ++j)                          \
            acc[i][j] = __builtin_amdgcn_mfma_f32_16x16x32_bf16(               \
                af[i], bfr[j], acc[i][j], 0, 0, 0);                            \
  }

  QKV_STAGE(0, 0);
  __syncthreads();
#pragma unroll 1
  for (int t = 0; t < 32; t += 2) {
    QKV_STAGE(1, (t + 1) * 32);
    QKV_COMPUTE(0);
    __syncthreads();
    if (t + 2 < 32) QKV_STAGE(0, (t + 2) * 32);
    QKV_COMPUTE(1);
    __syncthreads();
  }

  // epilogue
#pragma unroll
  for (int i = 0; i < 4; ++i) {
#pragma unroll
    for (int j = 0; j < 4; ++j) {
      int r0 = brow + wr + i * 16 + fq * 4;
      int cc = bcol + wc + j * 16 + fr;
      float bb = bias[cc];
      if (z < 2) {
        unsigned short* O = (z == 0) ? qo : ko;
#pragma unroll
        for (int q = 0; q < 4; ++q)
          O[(size_t)(r0 + q) * D_EMB + cc] = f2bf(acc[i][j][q] + bb);
      } else {
        int hh = cc >> 6, dd = cc & 63;
        int mm = r0 >> 11, tt = r0 & 2047;
        us4 pk;
#pragma unroll
        for (int q = 0; q < 4; ++q) pk[q] = f2bf(acc[i][j][q] + bb);
        *(us4*)&vto[((size_t)((mm * H_HEADS + hh) * 64 + dd)) * T_SEQ + tt] = pk;
      }
    }
  }
}

// ---------------- output projection GEMM ----------------
// 1D grid 512 blocks, XCD-swizzled. BM=128 BN=64 BK=32, bf16 A, fp32 out, dbuf.
__global__ __launch_bounds__(256) void out_gemm(const unsigned short* __restrict__ Ab,
                                                const unsigned short* __restrict__ Wb,
                                                const float* __restrict__ bias,
                                                float* __restrict__ Out) {
  const int swz = (blockIdx.x & 7) * 64 + (blockIdx.x >> 3);
  const int bx = swz & 15, by = swz >> 4;

  __shared__ __align__(16) unsigned short Asm[2][128 * 32];
  __shared__ __align__(16) unsigned short Bsm[2][64 * 32];
  const int tid = threadIdx.x;
  const int lane = tid & 63, w = tid >> 6;
  const int fq = lane >> 4, fr = lane & 15;
  const int brow = by * 128, bcol = bx * 64;
  const int wr = w * 32;

  f32x4 acc[2][4] = {};

#define OUT_STAGE(buf, k0)                                                     \
  {                                                                            \
    _Pragma("unroll") for (int it = 0; it < 2; ++it) {                         \
      int idx = it * 256 + tid;                                                \
      int row = idx >> 2, ce = (idx & 3) * 8;                                  \
      gl16(&Ab[(size_t)(brow + row) * D_EMB + (k0) + ce],                      \
           (char*)Asm[buf] + idx * 16);                                        \
    }                                                                          \
    {                                                                          \
      int row = tid >> 2, ce = (tid & 3) * 8;                                  \
      gl16(&Wb[(size_t)(bcol + row) * D_EMB + (k0) + ce],                      \
           (char*)Bsm[buf] + tid * 16);                                        \
    }                                                                          \
  }

#define OUT_COMPUTE(buf)                                                       \
  {                                                                            \
    bf16x8 af[2], bfr[4];                                                      \
    _Pragma("unroll") for (int i = 0; i < 2; ++i)                              \
        af[i] = *(const bf16x8*)((const char*)Asm[buf] +                       \
                                 (wr + i * 16 + fr) * 64 + fq * 16);           \
    _Pragma("unroll") for (int j = 0; j < 4; ++j)                              \
        bfr[j] = *(const bf16x8*)((const char*)Bsm[buf] +                      \
                                  (j * 16 + fr) * 64 + fq * 16);               \
    _Pragma("unroll") for (int i = 0; i < 2; ++i)                              \
        _Pragma("unroll") for (int j = 0; j < 4; ++j)                          \
            acc[i][j] = __builtin_amdgcn_mfma_f32_16x16x32_bf16(               \
                af[i], bfr[j], acc[i][j], 0, 0, 0);                            \
  }

  OUT_STAGE(0, 0);
  __syncthreads();
#pragma unroll 1
  for (int t = 0; t < 32; t += 2) {
    OUT_STAGE(1, (t + 1) * 32);
    OUT_COMPUTE(0);
    __syncthreads();
    if (t + 2 < 32) OUT_STAGE(0, (t + 2) * 32);
    OUT_COMPUTE(1);
    __syncthreads();
  }

#pragma unroll
  for (int i = 0; i < 2; ++i)
#pragma unroll
    for (int j = 0; j < 4; ++j) {
      int r0 = brow + wr + i * 16 + fq * 4;
      int cc = bcol + j * 16 + fr;
      float bb = bias[cc];
#pragma unroll
      for (int q = 0; q < 4; ++q)
        Out[(size_t)(r0 + q) * D_EMB + cc] = acc[i][j][q] + bb;
    }
}

// ---------------- Flash attention ----------------
// 1D grid 1024 blocks, XCD-swizzled (same (h,m) KV panel -> same XCD).
// block 256 (4 waves x 16 q-rows = 64 q-rows/block). KVBLK=128.
__global__ __launch_bounds__(256) void attn_fwd(const unsigned short* __restrict__ qb,
                                                const unsigned short* __restrict__ kb,
                                                const unsigned short* __restrict__ vtb,
                                                const int* __restrict__ maskg,
                                                unsigned short* __restrict__ outb) {
  const int swzb = (blockIdx.x & 7) * 128 + (blockIdx.x >> 3);
  const int qt = swzb & 31, h = (swzb >> 5) & 15, mI = swzb >> 9;
  const int tid = threadIdx.x;
  const int lane = tid & 63, w = tid >> 6;
  const int fq = lane >> 4, fr = lane & 15;
  const int x_fr = (fr & 7) << 4;

  __shared__ __align__(16) unsigned short Ksm[128 * 64];  // [t][d], swizzled
  __shared__ __align__(16) unsigned short Vsm[64 * 128];  // [d][t], swizzled
  __shared__ __align__(16) unsigned short Psm[4][16 * 128]; // per-wave [q][t], swizzled
  __shared__ __align__(16) float Msm[128];

  char* KsmB = (char*)Ksm;
  char* VsmB = (char*)Vsm;
  char* PsmB = (char*)Psm + w * 4096;

  const int qrow = qt * 64 + w * 16 + fr;
  bf16x8 qf[2];
#pragma unroll
  for (int kk = 0; kk < 2; ++kk)
    qf[kk] = *(const bf16x8*)&qb[((size_t)(mI * T_SEQ) + qrow) * D_EMB + h * 64 + kk * 32 + fq * 8];

  f32x4 o[4] = {};
  float mi = -1e30f, li = 0.f;

  const unsigned short* kpan = kb + (size_t)(mI * T_SEQ) * D_EMB + h * 64;
  const unsigned short* vpan = vtb + (size_t)(mI * H_HEADS + h) * 64 * T_SEQ;

  for (int k0 = 0; k0 < T_SEQ; k0 += 128) {
    // ---- stage K [128][64] ----
#pragma unroll
    for (int it = 0; it < 4; ++it) {
      int idx = it * 256 + tid;
      int row = idx >> 3;
      int sb = ((idx & 7) * 16) ^ ((row & 7) << 4);
      gl16(kpan + (size_t)(k0 + row) * D_EMB + (sb >> 1), KsmB + idx * 16);
    }
    // ---- stage Vt [64][128] ----
#pragma unroll
    for (int it = 0; it < 4; ++it) {
      int idx = it * 256 + tid;
      int row = idx >> 4;
      int sb = ((idx & 15) * 16) ^ ((row & 7) << 4);
      gl16(vpan + (size_t)row * T_SEQ + k0 + (sb >> 1), VsmB + idx * 16);
    }
    if (tid < 128) Msm[tid] = (maskg[mI * T_SEQ + k0 + tid] == 0) ? MASKNEG : 0.f;
    __syncthreads();

    // ---- S^T[key][q] = K · Q^T ----
    f32x4 s[8];
#pragma unroll
    for (int mt = 0; mt < 8; ++mt) {
      const char* kr = KsmB + (mt * 16 + fr) * 128;
      bf16x8 a0 = *(const bf16x8*)(kr + ((fq * 16) ^ x_fr));
      bf16x8 a1 = *(const bf16x8*)(kr + ((64 + fq * 16) ^ x_fr));
      f32x4 t = {};
      t = __builtin_amdgcn_mfma_f32_16x16x32_bf16(a0, qf[0], t, 0, 0, 0);
      t = __builtin_amdgcn_mfma_f32_16x16x32_bf16(a1, qf[1], t, 0, 0, 0);
      s[mt] = t;
    }

    // ---- scaled+masked logits (exp2 domain), tile max ----
    float tmax = -3e38f;
#pragma unroll
    for (int mt = 0; mt < 8; ++mt) {
      f32x4 mk = *(const f32x4*)&Msm[mt * 16 + fq * 4];
#pragma unroll
      for (int j = 0; j < 4; ++j) {
        float sv = fmaf(s[mt][j], SC2, mk[j]);
        s[mt][j] = sv;
        tmax = fmaxf(tmax, sv);
      }
    }
    tmax = fmaxf(tmax, __shfl_xor(tmax, 16));
    tmax = fmaxf(tmax, __shfl_xor(tmax, 32));

    // ---- defer-max rescale (THR=8 in log2 domain) ----
    if (__any(tmax > mi + 8.f)) {
      float mnew = fmaxf(mi, tmax);
      float corr = fexp2(mi - mnew);
#pragma unroll
      for (int nt = 0; nt < 4; ++nt) {
        o[nt][0] *= corr; o[nt][1] *= corr; o[nt][2] *= corr; o[nt][3] *= corr;
      }
      li *= corr;
      mi = mnew;
    }

    // ---- P = exp2(s - mi), row sum ----
    float ts = 0.f;
#pragma unroll
    for (int mt = 0; mt < 8; ++mt)
#pragma unroll
      for (int j = 0; j < 4; ++j) {
        float p = fexp2(s[mt][j] - mi);
        s[mt][j] = p;
        ts += p;
      }
    ts += __shfl_xor(ts, 16);
    ts += __shfl_xor(ts, 32);
    li += ts;

    // ---- pack P to bf16, store per-wave swizzled LDS [q=fr][key] ----
#pragma unroll
    for (int mt = 0; mt < 8; ++mt) {
      uint2 pw;
      pw.x = cvtpk(s[mt][0], s[mt][1]);
      pw.y = cvtpk(s[mt][2], s[mt][3]);
      *(uint2*)(PsmB + fr * 256 + ((mt * 32 + fq * 8) ^ x_fr)) = pw;
    }

    // ---- PV: o^T[d][q] += Vt · P ----
    bf16x8 pb[4];
#pragma unroll
    for (int kk = 0; kk < 4; ++kk)
      pb[kk] = *(const bf16x8*)(PsmB + fr * 256 + ((kk * 64 + fq * 16) ^ x_fr));
#pragma unroll
    for (int nt = 0; nt < 4; ++nt) {
      const char* vr = VsmB + (nt * 16 + fr) * 256;
#pragma unroll
      for (int kk = 0; kk < 4; ++kk) {
        bf16x8 va = *(const bf16x8*)(vr + ((kk * 64 + fq * 16) ^ x_fr));
        o[nt] = __builtin_amdgcn_mfma_f32_16x16x32_bf16(va, pb[kk], o[nt], 0, 0, 0);
      }
    }
    __syncthreads();
  }

  // ---- epilogue: divide by own-lane li, coalesced uint2 stores ----
  float inv = 1.f / li;
  size_t orow = (size_t)(mI * T_SEQ + qt * 64 + w * 16 + fr) * D_EMB + h * 64;
#pragma unroll
  for (int nt = 0; nt < 4; ++nt) {
    uint2 ow;
    ow.x = cvtpk(o[nt][0] * inv, o[nt][1] * inv);
    ow.y = cvtpk(o[nt][2] * inv, o[nt][3] * inv);
    *(uint2*)&outb[orow + nt * 16 + fq * 4] = ow;
  }
}

extern "C" void kernel_launch(void* const* d_in, const int* in_sizes, int n_in,
                              void* d_out, int out_size, void* d_ws, size_t ws_size,
                              hipStream_t stream) {
  const float* Q  = (const float*)d_in[0];
  const float* K  = (const float*)d_in[1];
  const float* V  = (const float*)d_in[2];
  const int* mask = (const int*)d_in[3];
  const float* Wq = (const float*)d_in[4];
  const float* bq = (const float*)d_in[5];
  const float* Wk = (const float*)d_in[6];
  const float* bk = (const float*)d_in[7];
  const float* Wv = (const float*)d_in[8];
  const float* bv = (const float*)d_in[9];
  const float* Wo = (const float*)d_in[10];
  const float* bo = (const float*)d_in[11];

  uint8_t* ws = (uint8_t*)d_ws;
  const size_t MB = 1u << 20;
  unsigned short* Wq_b = (unsigned short*)(ws + 0 * MB);
  unsigned short* Wk_b = (unsigned short*)(ws + 2 * MB);
  unsigned short* Wv_b = (unsigned short*)(ws + 4 * MB);
  unsigned short* Wo_b = (unsigned short*)(ws + 6 * MB);
  unsigned short* q_b  = (unsigned short*)(ws + 8 * MB);
  unsigned short* k_b  = (unsigned short*)(ws + 16 * MB);
  unsigned short* vt_b = (unsigned short*)(ws + 24 * MB);
  // Q_b/K_b/V_b (bf16 inputs) live at 32/40/48 MB; cc_b ALIASES Q_b (32 MB):
  // Q_b's last read (qkv_gemm) precedes cc_b's first write (attn_fwd).
  unsigned short* Qb   = (unsigned short*)(ws + 32 * MB);
  unsigned short* Kb   = (unsigned short*)(ws + 40 * MB);
  unsigned short* Vb   = (unsigned short*)(ws + 48 * MB);
  unsigned short* cc_b = (unsigned short*)(ws + 32 * MB);

  cvt_all<<<dim3(16384), dim3(256), 0, stream>>>(Q, K, V, Wq, Wk, Wv, Wo,
                                                 Qb, Kb, Vb, Wq_b, Wk_b, Wv_b, Wo_b);

  qkv_gemm<<<dim3(768), dim3(256), 0, stream>>>(
      Qb, Kb, Vb, Wq_b, Wk_b, Wv_b, bq, bk, bv, q_b, k_b, vt_b);

  attn_fwd<<<dim3(1024), dim3(256), 0, stream>>>(
      q_b, k_b, vt_b, mask, cc_b);

  out_gemm<<<dim3(512), dim3(256), 0, stream>>>(
      cc_b, Wo_b, bo, (float*)d_out);
}